// Round 5
// baseline (1180.531 us; speedup 1.0000x reference)
//
#include <hip/hip_runtime.h>
#include <hip/hip_bf16.h>

// ---------------------------------------------------------------------------
// Bidirectional GRU encoder (Keras reset_after=true), B=64 S=512 U=256 V=32000
//   k0a: wt_prep: W [256][768] fp32 -> Wtb [dir][768][256] bf16 (transposed)
//   k0b: u_prep : U fp32 -> fp16-pair blobs, 384B per gru thread
//   k1 : gx_mfma: gx = emb[x] @ W + b_in (+ b_rec for z,r), bf16 MFMA 16x16x32
//   k2 : gru: 128 wgs = (dir,batch), 1024 thr, launch_bounds(1024,4) ->
//        128-VGPR cap AND exactly 1 wg/CU (no 2-block packing).
//        thread = (unit-pair m, ks of 8): k-slice 32, U = 96 uints in VGPRs,
//        h fp16-pairs in LDS (8 regions, stride 20 ints = all 32 banks once),
//        double-buffered, 1 barrier/step, gx prefetched 1 step ahead.
// ws: [0, 100663296) gx ; +768K Wtb ; +768K Upk
// ---------------------------------------------------------------------------

typedef _Float16 half2v __attribute__((ext_vector_type(2)));
typedef short short8 __attribute__((ext_vector_type(8)));
typedef float f32x4 __attribute__((ext_vector_type(4)));

__device__ __forceinline__ unsigned short f2bf(float f) {
  unsigned int u = __float_as_uint(f);
  unsigned int r = (u + 0x7fffu + ((u >> 16) & 1u)) >> 16;  // RNE
  return (unsigned short)r;
}
__device__ __forceinline__ float bf2f(unsigned short v) {
  return __uint_as_float((unsigned int)v << 16);
}
__device__ __forceinline__ float blo(unsigned int u) { return __uint_as_float(u << 16); }
__device__ __forceinline__ float bhi(unsigned int u) { return __uint_as_float(u & 0xffff0000u); }
__device__ __forceinline__ unsigned int packf16(float a, float b) {
  half2v v = {(_Float16)a, (_Float16)b};
  return __builtin_bit_cast(unsigned int, v);
}
__device__ __forceinline__ float dot2(unsigned int u, unsigned int hv, float acc) {
#if __has_builtin(__builtin_amdgcn_fdot2)
  return __builtin_amdgcn_fdot2(__builtin_bit_cast(half2v, u),
                                __builtin_bit_cast(half2v, hv), acc, false);
#else
  half2v a = __builtin_bit_cast(half2v, u), b = __builtin_bit_cast(half2v, hv);
  return acc + (float)a.x * (float)b.x + (float)a.y * (float)b.y;
#endif
}

// ---------------- k0a: Wtb[dir][c][k] = bf16(W[k][c]) -----------------------
__global__ void __launch_bounds__(256) wt_prep_kernel(const float* __restrict__ Wf,
                                                      const float* __restrict__ Wb,
                                                      unsigned short* __restrict__ Wtb) {
  int o = blockIdx.x * 256 + threadIdx.x;
  if (o >= 2 * 768 * 256) return;
  int dir = o / (768 * 256);
  int rem = o % (768 * 256);
  int c = rem / 256, k = rem % 256;
  const float* W = dir ? Wb : Wf;
  Wtb[o] = f2bf(W[(size_t)k * 768 + c]);
}

// ---------------- k0b: per-thread U blobs -----------------------------------
// blob[id=dir*1024+t][96]: t=(m<<3)|ks; order [z0,z1,r0,r1,h0,h1] x 16 pairs;
// pair p of gate g, unit j=2m+s: pack(U[32ks+2p][g*256+j], U[32ks+2p+1][...])
__global__ void __launch_bounds__(256) u_prep_kernel(const float* __restrict__ Uf,
                                                     const float* __restrict__ Ub,
                                                     unsigned int* __restrict__ Upk) {
  int id = blockIdx.x * 256 + threadIdx.x;   // 0..2047
  if (id >= 2048) return;
  int dir = id >> 10, t = id & 1023;
  int m = t >> 3, ks = t & 7;
  const float* U = dir ? Ub : Uf;
  unsigned int* o = Upk + (size_t)id * 96;
#pragma unroll
  for (int g = 0; g < 3; ++g)
#pragma unroll
    for (int s = 0; s < 2; ++s) {
      int col = g * 256 + 2 * m + s;
#pragma unroll
      for (int p = 0; p < 16; ++p) {
        int k = ks * 32 + 2 * p;
        o[(g * 2 + s) * 16 + p] =
            packf16(U[(size_t)k * 768 + col], U[(size_t)(k + 1) * 768 + col]);
      }
    }
}

// ---------------- k1: gx = emb[x] @ W + bias, bf16 MFMA ---------------------
__global__ void __launch_bounds__(256) gx_mfma_kernel(
    const int* __restrict__ x, const float* __restrict__ emb,
    const unsigned short* __restrict__ Wtb,
    const float* __restrict__ bfv, const float* __restrict__ bbv,
    unsigned short* __restrict__ gx) {
  __shared__ __align__(16) unsigned short As[128 * 32];
  __shared__ __align__(16) unsigned short Bs[128 * 32];
  __shared__ int xid[128];

  int tid = threadIdx.x;
  int r0 = blockIdx.x * 128;
  int yt = blockIdx.y;
  int dir = (yt >= 6) ? 1 : 0;
  int c0 = (yt - dir * 6) * 128;
  const float* bv = dir ? bbv : bfv;
  const unsigned short* WtD = Wtb + (size_t)dir * 768 * 256;

  if (tid < 128) xid[tid] = x[r0 + tid];
  __syncthreads();

  int lane = tid & 63, w = tid >> 6;
  int wr = w >> 1, wc = w & 1;

  f32x4 acc[4][4] = {};

  for (int ks = 0; ks < 8; ++ks) {
#pragma unroll
    for (int i = 0; i < 2; ++i) {
      int s = tid + i * 256;
      int row = s >> 2, kslot = s & 3;
      int sw = kslot ^ ((row >> 2) & 3);
      const float* src = emb + (size_t)xid[row] * 256 + ks * 32 + kslot * 8;
      float4 f0 = *(const float4*)src;
      float4 f1 = *(const float4*)(src + 4);
      uint4 pa;
      pa.x = f2bf(f0.x) | ((unsigned)f2bf(f0.y) << 16);
      pa.y = f2bf(f0.z) | ((unsigned)f2bf(f0.w) << 16);
      pa.z = f2bf(f1.x) | ((unsigned)f2bf(f1.y) << 16);
      pa.w = f2bf(f1.z) | ((unsigned)f2bf(f1.w) << 16);
      *(uint4*)&As[row * 32 + sw * 8] = pa;
      uint4 pb = *(const uint4*)(WtD + (size_t)(c0 + row) * 256 + ks * 32 + kslot * 8);
      *(uint4*)&Bs[row * 32 + sw * 8] = pb;
    }
    __syncthreads();

    short8 a[4], b[4];
#pragma unroll
    for (int f = 0; f < 4; ++f) {
      int rowA = wr * 64 + f * 16 + (lane & 15);
      int swA = (lane >> 4) ^ ((rowA >> 2) & 3);
      a[f] = __builtin_bit_cast(short8, *(const uint4*)&As[rowA * 32 + swA * 8]);
      int rowB = wc * 64 + f * 16 + (lane & 15);
      int swB = (lane >> 4) ^ ((rowB >> 2) & 3);
      b[f] = __builtin_bit_cast(short8, *(const uint4*)&Bs[rowB * 32 + swB * 8]);
    }
#pragma unroll
    for (int fm = 0; fm < 4; ++fm)
#pragma unroll
      for (int fn = 0; fn < 4; ++fn)
        acc[fm][fn] = __builtin_amdgcn_mfma_f32_16x16x32_bf16(a[fm], b[fn], acc[fm][fn], 0, 0, 0);
    __syncthreads();
  }

#pragma unroll
  for (int fn = 0; fn < 4; ++fn) {
    int col = c0 + wc * 64 + fn * 16 + (lane & 15);
    float bias = bv[col] + (col < 512 ? bv[768 + col] : 0.f);
#pragma unroll
    for (int fm = 0; fm < 4; ++fm) {
      int rowb = r0 + wr * 64 + fm * 16 + (lane >> 4) * 4;
#pragma unroll
      for (int q = 0; q < 4; ++q) {
        gx[((size_t)dir * 32768 + rowb + q) * 768 + col] = f2bf(acc[fm][fn][q] + bias);
      }
    }
  }
}

// ---------------- k2: recurrence ---------------------------------------------
__global__ void __launch_bounds__(1024, 4) gru_kernel(
    const unsigned int* __restrict__ Upk,    // [2*1024][96] fp16 pairs
    const unsigned short* __restrict__ gx,   // [2][32768][768] bf16
    const int* __restrict__ x,
    const float* __restrict__ bfv, const float* __restrict__ bbv,
    float* __restrict__ out) {
  int wg = blockIdx.x;
  int dir = wg >> 6, b = wg & 63;
  int t = threadIdx.x;
  int m = t >> 3;            // unit pair 0..127 (units 2m, 2m+1)
  int ks = t & 7;            // k-slice [32ks, 32ks+32)
  int j0 = 2 * m;

  // h fp16 pairs: 8 regions of 16 ints, stride 20 -> wave's 8 b128 addrs
  // cover all 32 banks exactly once. Double-buffered.
  __shared__ unsigned int h_buf[2][160];

  const float* bv = dir ? bbv : bfv;
  const float brh0 = bv[768 + 512 + j0];
  const float brh1 = bv[768 + 512 + j0 + 1];
  const unsigned short* gxd = gx + ((size_t)dir * 32768 + (size_t)b * 512) * 768;
  const int* xb = x + b * 512;
  float* outb = out + (size_t)b * 512 * 256;

  // one-time: 24 coalesced uint4 loads of this thread's U blob
  unsigned int uz0[16], uz1[16], ur0[16], ur1[16], uh0[16], uh1[16];
  {
    const uint4* us = (const uint4*)(Upk + ((size_t)(dir << 10) + t) * 96);
#pragma unroll
    for (int q = 0; q < 4; ++q) { uint4 v = us[q];      uz0[4*q]=v.x; uz0[4*q+1]=v.y; uz0[4*q+2]=v.z; uz0[4*q+3]=v.w; }
#pragma unroll
    for (int q = 0; q < 4; ++q) { uint4 v = us[4 + q];  uz1[4*q]=v.x; uz1[4*q+1]=v.y; uz1[4*q+2]=v.z; uz1[4*q+3]=v.w; }
#pragma unroll
    for (int q = 0; q < 4; ++q) { uint4 v = us[8 + q];  ur0[4*q]=v.x; ur0[4*q+1]=v.y; ur0[4*q+2]=v.z; ur0[4*q+3]=v.w; }
#pragma unroll
    for (int q = 0; q < 4; ++q) { uint4 v = us[12 + q]; ur1[4*q]=v.x; ur1[4*q+1]=v.y; ur1[4*q+2]=v.z; ur1[4*q+3]=v.w; }
#pragma unroll
    for (int q = 0; q < 4; ++q) { uint4 v = us[16 + q]; uh0[4*q]=v.x; uh0[4*q+1]=v.y; uh0[4*q+2]=v.z; uh0[4*q+3]=v.w; }
#pragma unroll
    for (int q = 0; q < 4; ++q) { uint4 v = us[20 + q]; uh1[4*q]=v.x; uh1[4*q+1]=v.y; uh1[4*q+2]=v.z; uh1[4*q+3]=v.w; }
  }
  if (t < 320) ((unsigned int*)h_buf)[t] = 0u;
  __syncthreads();

  // prologue: preload step 0's gx (packed dwords: 2 units per load) + mask
  int tt0 = dir ? 511 : 0;
  const unsigned int* g0 = (const unsigned int*)(gxd + (size_t)tt0 * 768);
  unsigned int vz = g0[m], vr = g0[128 + m], vh = g0[256 + m];
  int xv = xb[tt0];

  float hj0 = 0.f, hj1 = 0.f;
  int cur = 0;
  for (int step = 0; step < 512; ++step) {
    int tcur = dir ? (511 - step) : step;
    // prefetch next step (latency hidden under dot loop)
    unsigned int vz_n = 0u, vr_n = 0u, vh_n = 0u;
    int xv_n = 0;
    if (step < 511) {
      int tn = dir ? (510 - step) : (step + 1);
      const unsigned int* gn = (const unsigned int*)(gxd + (size_t)tn * 768);
      vz_n = gn[m]; vr_n = gn[128 + m]; vh_n = gn[256 + m];
      xv_n = xb[tn];
    }

    float az0 = 0.f, az1 = 0.f, ar0 = 0.f, ar1 = 0.f, ah0 = 0.f, ah1 = 0.f;
    const unsigned int* hb = &h_buf[cur][ks * 20];
#pragma unroll
    for (int c = 0; c < 4; ++c) {
      uint4 hv = *(const uint4*)&hb[c * 4];   // 8 addrs/wave, all 32 banks once
#pragma unroll
      for (int w = 0; w < 4; ++w) {
        unsigned int hw = (w == 0) ? hv.x : (w == 1) ? hv.y : (w == 2) ? hv.z : hv.w;
        int p = c * 4 + w;
        az0 = dot2(uz0[p], hw, az0);
        az1 = dot2(uz1[p], hw, az1);
        ar0 = dot2(ur0[p], hw, ar0);
        ar1 = dot2(ur1[p], hw, ar1);
        ah0 = dot2(uh0[p], hw, ah0);
        ah1 = dot2(uh1[p], hw, ah1);
      }
    }
    // butterfly over the 8 k-slices (lanes ks^1, ks^2, ks^4)
#define RED8(v) v += __shfl_xor(v, 1); v += __shfl_xor(v, 2); v += __shfl_xor(v, 4);
    RED8(az0) RED8(az1) RED8(ar0) RED8(ar1) RED8(ah0) RED8(ah1)
#undef RED8

    float gz0 = blo(vz), gz1 = bhi(vz);
    float gr0 = blo(vr), gr1 = bhi(vr);
    float gh0 = blo(vh), gh1 = bhi(vh);

    float z0 = 1.f / (1.f + __expf(-(gz0 + az0)));
    float r0 = 1.f / (1.f + __expf(-(gr0 + ar0)));
    float e0 = __expf(2.f * (gh0 + r0 * (ah0 + brh0)));
    float hh0 = (e0 - 1.f) / (e0 + 1.f);
    float hn0 = z0 * hj0 + (1.f - z0) * hh0;
    hn0 = (xv == 0) ? hj0 : hn0;

    float z1 = 1.f / (1.f + __expf(-(gz1 + az1)));
    float r1 = 1.f / (1.f + __expf(-(gr1 + ar1)));
    float e1 = __expf(2.f * (gh1 + r1 * (ah1 + brh1)));
    float hh1 = (e1 - 1.f) / (e1 + 1.f);
    float hn1 = z1 * hj1 + (1.f - z1) * hh1;
    hn1 = (xv == 0) ? hj1 : hn1;

    if (ks == 0)   // writer: region m>>4, offset m&15; banks distinct per wave
      h_buf[cur ^ 1][(m >> 4) * 20 + (m & 15)] = packf16(hn0, hn1);
    __syncthreads();                           // one barrier per step

    if (ks == 0) {
      atomicAdd(&outb[(size_t)tcur * 256 + j0], hn0);
      atomicAdd(&outb[(size_t)tcur * 256 + j0 + 1], hn1);
    }
    hj0 = hn0; hj1 = hn1;
    vz = vz_n; vr = vr_n; vh = vh_n; xv = xv_n;
    cur ^= 1;
  }
}

// ---------------------------------------------------------------------------
extern "C" void kernel_launch(void* const* d_in, const int* in_sizes, int n_in,
                              void* d_out, int out_size, void* d_ws, size_t ws_size,
                              hipStream_t stream) {
  const int*   x   = (const int*)d_in[0];
  const float* emb = (const float*)d_in[1];
  const float* Wf  = (const float*)d_in[2];
  const float* Uf  = (const float*)d_in[3];
  const float* bf_ = (const float*)d_in[4];
  const float* Wb  = (const float*)d_in[5];
  const float* Ub  = (const float*)d_in[6];
  const float* bb_ = (const float*)d_in[7];
  float* out = (float*)d_out;

  unsigned short* gxp = (unsigned short*)d_ws;                        // 100.66 MB
  unsigned short* Wtb = (unsigned short*)((char*)d_ws + 100663296);   // 768 KB
  unsigned int*   Upk = (unsigned int*)((char*)d_ws + 100663296 + 786432);  // 768 KB

  hipMemsetAsync(d_out, 0, (size_t)out_size * sizeof(float), stream);

  wt_prep_kernel<<<1536, 256, 0, stream>>>(Wf, Wb, Wtb);
  u_prep_kernel<<<8, 256, 0, stream>>>(Uf, Ub, Upk);
  gx_mfma_kernel<<<dim3(256, 12), 256, 0, stream>>>(x, emb, Wtb, bf_, bb_, gxp);
  gru_kernel<<<128, 1024, 0, stream>>>(Upk, gxp, x, bf_, bb_, out);
}